// Round 1
// baseline (138.287 us; speedup 1.0000x reference)
//
#include <hip/hip_runtime.h>
#include <hip/hip_bf16.h>

#define B_ 8
#define N_ 4096
#define M_ 4096
#define D_ 64
#define BNT (B_ * N_)   // 32768
#define BMT (B_ * M_)   // 32768

typedef short bf16x8 __attribute__((ext_vector_type(8)));
typedef float f32x4 __attribute__((ext_vector_type(4)));

__device__ __forceinline__ unsigned short f2bf(float f) {
  __hip_bfloat16 h = __float2bfloat16(f);
  return *reinterpret_cast<unsigned short*>(&h);
}

// Kernel 1: per-row squared norms (fp32) + init min arrays to +inf.
// 16 rows per 256-thread block; 16 lanes per row, one float4 each.
__global__ __launch_bounds__(256) void norms_init_kernel(
    const float* __restrict__ pred, const float* __restrict__ label,
    float* __restrict__ x2, float* __restrict__ y2,
    int* __restrict__ minN, int* __restrict__ minM) {
  int t = threadIdx.x;
  int lane = t & 15;
  long row = (long)blockIdx.x * 16 + (t >> 4);
  const float4* src;
  float* dst;
  int* mdst;
  if (row < BNT) {
    src = reinterpret_cast<const float4*>(pred + row * D_);
    dst = x2 + row;
    mdst = minN + row;
  } else {
    long r2 = row - BNT;
    src = reinterpret_cast<const float4*>(label + r2 * D_);
    dst = y2 + r2;
    mdst = minM + r2;
  }
  float4 v = src[lane];
  float s = v.x * v.x + v.y * v.y + v.z * v.z + v.w * v.w;
  s += __shfl_xor(s, 1);
  s += __shfl_xor(s, 2);
  s += __shfl_xor(s, 4);
  s += __shfl_xor(s, 8);
  if (lane == 0) {
    *dst = s;
    *mdst = 0x7f800000;  // +inf bits
  }
}

// Kernel 2: 128x128 tile per block, bf16 MFMA for the gram term,
// fused min-reduction along both axes, atomicMin into global min arrays.
__global__ __launch_bounds__(256) void haus_main_kernel(
    const float* __restrict__ pred, const float* __restrict__ label,
    const float* __restrict__ x2, const float* __restrict__ y2,
    int* __restrict__ minN, int* __restrict__ minM) {
  // LDS: swizzled bf16 tiles [128 rows][64 d], row pitch 128B.
  __shared__ unsigned short Abf[128 * 64];
  __shared__ unsigned short Bbf[128 * 64];
  __shared__ float x2l[128];
  __shared__ float y2l[128];

  const int t = threadIdx.x;
  const int b = blockIdx.z;
  const int n0 = blockIdx.y * 128;
  const int m0 = blockIdx.x * 128;

  const float4* A4 = reinterpret_cast<const float4*>(pred + ((size_t)b * N_ + n0) * D_);
  const float4* B4 = reinterpret_cast<const float4*>(label + ((size_t)b * M_ + m0) * D_);

  // ---- stage fp32 -> bf16 into swizzled LDS (coalesced flat loads) ----
  const int dly = (t & 15) * 8;  // byte offset of this thread's 4-elem group in a row
  #pragma unroll
  for (int i = 0; i < 8; i++) {
    int off = i * 256 + t;       // float4 index, fully coalesced
    float4 a = A4[off];
    float4 bb = B4[off];
    int row = i * 16 + (t >> 4);
    int ba = (row * 128 + dly) ^ ((row & 7) << 4);  // XOR swizzle (G4)
    ushort4 pa;
    pa.x = f2bf(a.x); pa.y = f2bf(a.y); pa.z = f2bf(a.z); pa.w = f2bf(a.w);
    ushort4 pb;
    pb.x = f2bf(bb.x); pb.y = f2bf(bb.y); pb.z = f2bf(bb.z); pb.w = f2bf(bb.w);
    *reinterpret_cast<ushort4*>(reinterpret_cast<char*>(Abf) + ba) = pa;
    *reinterpret_cast<ushort4*>(reinterpret_cast<char*>(Bbf) + ba) = pb;
  }
  if (t < 128) {
    x2l[t] = x2[(size_t)b * N_ + n0 + t];
  } else {
    y2l[t - 128] = y2[(size_t)b * M_ + m0 + (t - 128)];
  }
  __syncthreads();

  // ---- MFMA: 4 waves, each a 64x64 sub-tile (4x4 fragments of 16x16) ----
  const int w = t >> 6;
  const int l = t & 63;
  const int wr = w >> 1, wc = w & 1;
  const int g = l >> 4, c = l & 15;

  f32x4 acc[4][4];
  #pragma unroll
  for (int mi = 0; mi < 4; mi++)
    #pragma unroll
    for (int ni = 0; ni < 4; ni++)
      acc[mi][ni] = (f32x4){0.f, 0.f, 0.f, 0.f};

  #pragma unroll
  for (int kk = 0; kk < 2; kk++) {
    bf16x8 af[4], bfr[4];
    #pragma unroll
    for (int mi = 0; mi < 4; mi++) {
      int r = wr * 64 + mi * 16 + c;
      int ba = (r * 128 + kk * 64 + g * 16) ^ ((r & 7) << 4);
      af[mi] = *reinterpret_cast<const bf16x8*>(reinterpret_cast<const char*>(Abf) + ba);
    }
    #pragma unroll
    for (int ni = 0; ni < 4; ni++) {
      int r = wc * 64 + ni * 16 + c;
      int ba = (r * 128 + kk * 64 + g * 16) ^ ((r & 7) << 4);
      bfr[ni] = *reinterpret_cast<const bf16x8*>(reinterpret_cast<const char*>(Bbf) + ba);
    }
    #pragma unroll
    for (int mi = 0; mi < 4; mi++)
      #pragma unroll
      for (int ni = 0; ni < 4; ni++)
        acc[mi][ni] = __builtin_amdgcn_mfma_f32_16x16x32_bf16(af[mi], bfr[ni], acc[mi][ni], 0, 0, 0);
  }

  // ---- epilogue: sq = x2 + y2 - 2*xy; min along rows (over m) and cols (over n) ----
  // C/D layout (m89): col = lane&15 (m-dir), row = (lane>>4)*4 + e (n-dir)
  float x2v[4][4];
  #pragma unroll
  for (int mi = 0; mi < 4; mi++)
    #pragma unroll
    for (int e = 0; e < 4; e++)
      x2v[mi][e] = x2l[wr * 64 + mi * 16 + g * 4 + e];
  float y2v[4];
  #pragma unroll
  for (int ni = 0; ni < 4; ni++) y2v[ni] = y2l[wc * 64 + ni * 16 + c];

  float rmin[4][4];
  float cmin[4];
  #pragma unroll
  for (int mi = 0; mi < 4; mi++)
    #pragma unroll
    for (int e = 0; e < 4; e++) rmin[mi][e] = INFINITY;
  #pragma unroll
  for (int ni = 0; ni < 4; ni++) cmin[ni] = INFINITY;

  #pragma unroll
  for (int mi = 0; mi < 4; mi++)
    #pragma unroll
    for (int ni = 0; ni < 4; ni++)
      #pragma unroll
      for (int e = 0; e < 4; e++) {
        float v = fmaxf(x2v[mi][e] + y2v[ni] - 2.f * acc[mi][ni][e], 0.f);
        rmin[mi][e] = fminf(rmin[mi][e], v);
        cmin[ni] = fminf(cmin[ni], v);
      }

  // row-min: reduce across the 16 column-lanes (masks 1,2,4,8)
  #pragma unroll
  for (int mi = 0; mi < 4; mi++)
    #pragma unroll
    for (int e = 0; e < 4; e++) {
      float r = rmin[mi][e];
      r = fminf(r, __shfl_xor(r, 1));
      r = fminf(r, __shfl_xor(r, 2));
      r = fminf(r, __shfl_xor(r, 4));
      r = fminf(r, __shfl_xor(r, 8));
      rmin[mi][e] = r;
    }
  if (c == 0) {
    #pragma unroll
    for (int mi = 0; mi < 4; mi++)
      #pragma unroll
      for (int e = 0; e < 4; e++)
        atomicMin(&minN[(size_t)b * N_ + n0 + wr * 64 + mi * 16 + g * 4 + e],
                  __float_as_int(rmin[mi][e]));
  }
  // col-min: reduce across the 4 row-groups (masks 16,32)
  #pragma unroll
  for (int ni = 0; ni < 4; ni++) {
    float r = cmin[ni];
    r = fminf(r, __shfl_xor(r, 16));
    r = fminf(r, __shfl_xor(r, 32));
    cmin[ni] = r;
  }
  if (g == 0) {
    #pragma unroll
    for (int ni = 0; ni < 4; ni++)
      atomicMin(&minM[(size_t)b * M_ + m0 + wc * 64 + ni * 16 + c],
                __float_as_int(cmin[ni]));
  }
}

// Kernel 3: max over both min-arrays, sqrt at the end (monotone), sum -> out.
__global__ __launch_bounds__(1024) void final_kernel(
    const int* __restrict__ minN, const int* __restrict__ minM,
    float* __restrict__ out) {
  __shared__ float smx[16], smy[16];
  int t = threadIdx.x;
  float mx = 0.f, my = 0.f;
  for (int i = t; i < BNT; i += 1024) mx = fmaxf(mx, __int_as_float(minN[i]));
  for (int i = t; i < BMT; i += 1024) my = fmaxf(my, __int_as_float(minM[i]));
  #pragma unroll
  for (int mask = 1; mask < 64; mask <<= 1) {
    mx = fmaxf(mx, __shfl_xor(mx, mask));
    my = fmaxf(my, __shfl_xor(my, mask));
  }
  if ((t & 63) == 0) {
    smx[t >> 6] = mx;
    smy[t >> 6] = my;
  }
  __syncthreads();
  if (t == 0) {
    float a = 0.f, bm = 0.f;
    for (int i = 0; i < 16; i++) {
      a = fmaxf(a, smx[i]);
      bm = fmaxf(bm, smy[i]);
    }
    out[0] = sqrtf(fmaxf(a, 1e-12f)) + sqrtf(fmaxf(bm, 1e-12f));
  }
}

extern "C" void kernel_launch(void* const* d_in, const int* in_sizes, int n_in,
                              void* d_out, int out_size, void* d_ws, size_t ws_size,
                              hipStream_t stream) {
  const float* pred = (const float*)d_in[0];
  const float* label = (const float*)d_in[1];
  float* ws = (float*)d_ws;
  float* x2 = ws;                       // 32768 f32
  float* y2 = ws + BNT;                 // 32768 f32
  int* minN = (int*)(ws + BNT + BMT);   // 32768 f32-as-int
  int* minM = minN + BNT;               // 32768 f32-as-int
  float* out = (float*)d_out;

  norms_init_kernel<<<(BNT + BMT) / 16, 256, 0, stream>>>(pred, label, x2, y2, minN, minM);
  haus_main_kernel<<<dim3(M_ / 128, N_ / 128, B_), 256, 0, stream>>>(pred, label, x2, y2, minN, minM);
  final_kernel<<<1, 1024, 0, stream>>>(minN, minM, out);
}

// Round 2
// 63.317 us; speedup vs baseline: 2.1840x; 2.1840x over previous
//
#include <hip/hip_runtime.h>
#include <hip/hip_bf16.h>

#define B_ 8
#define N_ 4096
#define M_ 4096
#define D_ 64
#define BNT (B_ * N_)   // 32768
#define BMT (B_ * M_)   // 32768
#define TILE 128
#define CHUNK_TILES 8
#define NCHUNK (M_ / (TILE * CHUNK_TILES))  // 4

typedef short bf16x8 __attribute__((ext_vector_type(8)));
typedef float f32x4 __attribute__((ext_vector_type(4)));

__device__ __forceinline__ unsigned short f2bf(float f) {
  __hip_bfloat16 h = __float2bfloat16(f);
  return *reinterpret_cast<unsigned short*>(&h);
}

// Order-preserving float -> uint key: works with atomicMin/atomicMax(unsigned)
// even for negative floats (raw float-bit int compare is reversed on negatives).
__device__ __forceinline__ unsigned fkey(float f) {
  unsigned b = __float_as_uint(f);
  return b ^ ((unsigned)((int)b >> 31) | 0x80000000u);
}
__device__ __forceinline__ float funkey(unsigned k) {
  unsigned b = (k & 0x80000000u) ? (k ^ 0x80000000u) : ~k;
  return __uint_as_float(b);
}

__device__ __forceinline__ void gload_lds16(const void* g, void* l) {
  __builtin_amdgcn_global_load_lds(
      (const __attribute__((address_space(1))) unsigned int*)g,
      (__attribute__((address_space(3))) unsigned int*)l, 16, 0, 0);
}

// Stage one 128x64 bf16 tile into swizzled LDS.
// BF=true : source is bf16, direct global->LDS DMA, source pre-swizzled (m173).
// BF=false: source is fp32, VALU convert + swizzled ds_write (fallback).
template <bool BF>
__device__ __forceinline__ void stage_tile(const void* gsrc, unsigned short* lds,
                                           int t, int srcpat) {
  if (BF) {
    const char* gp = (const char*)gsrc;
    int w = t >> 6;
#pragma unroll
    for (int i = 0; i < 4; i++) {
      int q = w * 4 + i;
      gload_lds16(gp + q * 1024 + srcpat, (char*)lds + q * 1024);
    }
  } else {
    const float4* g4 = (const float4*)gsrc;
#pragma unroll
    for (int i = 0; i < 8; i++) {
      int off = i * 256 + t;  // float4 index within the 128x64 tile
      float4 v = g4[off];
      int row = off >> 4;
      int cb = (off & 15) * 8;
      int ba = (row * 128 + cb) ^ ((row & 7) << 4);
      ushort4 p;
      p.x = f2bf(v.x); p.y = f2bf(v.y); p.z = f2bf(v.z); p.w = f2bf(v.w);
      *(ushort4*)((char*)lds + ba) = p;
    }
  }
}

// Kernel 1: norms + init (+ optional fp32->bf16 conversion).
template <bool CONV>
__global__ __launch_bounds__(256) void prep_kernel(
    const float* __restrict__ pred, const float* __restrict__ label,
    unsigned short* __restrict__ predbf, unsigned short* __restrict__ labelbf,
    float* __restrict__ x2, float* __restrict__ y2,
    unsigned* __restrict__ minN, unsigned* __restrict__ minM,
    unsigned* __restrict__ gmax) {
  int t = threadIdx.x;
  int lane = t & 15;
  long row = (long)blockIdx.x * 16 + (t >> 4);
  const float4* src;
  unsigned short* bdst;
  float* ndst;
  unsigned* mdst;
  if (row < BNT) {
    src = (const float4*)(pred + row * D_);
    bdst = predbf + row * D_;
    ndst = x2 + row;
    mdst = minN + row;
  } else {
    long r2 = row - BNT;
    src = (const float4*)(label + r2 * D_);
    bdst = labelbf + r2 * D_;
    ndst = y2 + r2;
    mdst = minM + r2;
  }
  float4 v = src[lane];
  if (CONV) {
    ushort4 p;
    p.x = f2bf(v.x); p.y = f2bf(v.y); p.z = f2bf(v.z); p.w = f2bf(v.w);
    *(ushort4*)(bdst + lane * 4) = p;
  }
  float s = v.x * v.x + v.y * v.y + v.z * v.z + v.w * v.w;
  s += __shfl_xor(s, 1);
  s += __shfl_xor(s, 2);
  s += __shfl_xor(s, 4);
  s += __shfl_xor(s, 8);
  if (lane == 0) {
    *ndst = s;
    *mdst = 0xFFFFFFFFu;  // +inf key
  }
  if (blockIdx.x == 0 && t < 2) gmax[t] = 0u;  // below fkey of any real value's max
}

// Kernel 2 (run twice with roles swapped): block owns a 128-row A-band,
// loops over 8 B-tiles; computes rmin[row] = min over these B rows of
// (||b||^2 - 2<a,b>) and atomicMin's the key into minOut.
template <bool BF>
__global__ __launch_bounds__(256) void pass_kernel(
    const void* __restrict__ Asrc,   // bf16 (BF) or fp32 rows [B][4096][64]
    const void* __restrict__ Bsrc,
    const float* __restrict__ normB,  // [B][4096]
    unsigned* __restrict__ minOut) {  // [B][4096] keys
  __shared__ alignas(16) unsigned short As[TILE * 64];
  __shared__ alignas(16) unsigned short Bs[TILE * 64];

  const int t = threadIdx.x;
  const int b = blockIdx.z;
  const int a0 = blockIdx.x * TILE;
  const int w = t >> 6, l = t & 63;
  const int g = l >> 4, c = l & 15;

  // per-lane pre-swizzled source byte offset inside a 1024B chunk (BF path)
  const int srcpat = (l >> 3) * 128 + (((l & 7) * 16) ^ ((l >> 3) << 4));

  const size_t rowbytes = BF ? 128 : 256;
  const char* Agl = (const char*)Asrc + ((size_t)b * N_ + a0) * rowbytes;
  const char* Bgl = (const char*)Bsrc + (size_t)b * M_ * rowbytes;

  stage_tile<BF>(Agl, As, t, srcpat);
  stage_tile<BF>(Bgl + (size_t)(blockIdx.y * CHUNK_TILES) * TILE * rowbytes, Bs, t, srcpat);
  __syncthreads();

  // A fragments held in registers for the whole loop.
  bf16x8 af[2][2];  // [kk][mi]
#pragma unroll
  for (int kk = 0; kk < 2; kk++)
#pragma unroll
    for (int mi = 0; mi < 2; mi++) {
      int r = w * 32 + mi * 16 + c;
      int ba = (r * 128 + kk * 64 + g * 16) ^ ((r & 7) << 4);
      af[kk][mi] = *(const bf16x8*)((const char*)As + ba);
    }

  float rmin[2][4];
#pragma unroll
  for (int mi = 0; mi < 2; mi++)
#pragma unroll
    for (int e = 0; e < 4; e++) rmin[mi][e] = INFINITY;

  for (int it = 0; it < CHUNK_TILES; it++) {
    const int m0 = (blockIdx.y * CHUNK_TILES + it) * TILE;

    float nbv[8];
#pragma unroll
    for (int ni = 0; ni < 8; ni++)
      nbv[ni] = normB[(size_t)b * M_ + m0 + ni * 16 + c];

    f32x4 acc[2][8];
#pragma unroll
    for (int kk = 0; kk < 2; kk++) {
      bf16x8 bfr[8];
#pragma unroll
      for (int ni = 0; ni < 8; ni++) {
        int r = ni * 16 + c;
        int ba = (r * 128 + kk * 64 + g * 16) ^ ((r & 7) << 4);
        bfr[ni] = *(const bf16x8*)((const char*)Bs + ba);
      }
#pragma unroll
      for (int mi = 0; mi < 2; mi++)
#pragma unroll
        for (int ni = 0; ni < 8; ni++) {
          if (kk == 0)
            acc[mi][ni] = __builtin_amdgcn_mfma_f32_16x16x32_bf16(
                af[0][mi], bfr[ni], (f32x4){0.f, 0.f, 0.f, 0.f}, 0, 0, 0);
          else
            acc[mi][ni] = __builtin_amdgcn_mfma_f32_16x16x32_bf16(
                af[1][mi], bfr[ni], acc[mi][ni], 0, 0, 0);
        }
    }
    __syncthreads();  // all Bs reads retired (lgkm drained) -> buffer free

    if (it + 1 < CHUNK_TILES)
      stage_tile<BF>(Bgl + (size_t)(blockIdx.y * CHUNK_TILES + it + 1) * TILE * rowbytes,
                     Bs, t, srcpat);

    // register-only epilogue runs while the stage is in flight
#pragma unroll
    for (int mi = 0; mi < 2; mi++)
#pragma unroll
      for (int ni = 0; ni < 8; ni++)
#pragma unroll
        for (int e = 0; e < 4; e++)
          rmin[mi][e] = fminf(rmin[mi][e], fmaf(-2.f, acc[mi][ni][e], nbv[ni]));

    __syncthreads();  // stage landed (vmcnt drained before barrier)
  }

  // reduce over the 16 column-lanes, then one atomic per A-row
#pragma unroll
  for (int mi = 0; mi < 2; mi++)
#pragma unroll
    for (int e = 0; e < 4; e++) {
      float r = rmin[mi][e];
      r = fminf(r, __shfl_xor(r, 1));
      r = fminf(r, __shfl_xor(r, 2));
      r = fminf(r, __shfl_xor(r, 4));
      r = fminf(r, __shfl_xor(r, 8));
      rmin[mi][e] = r;
    }
  if (c == 0) {
#pragma unroll
    for (int mi = 0; mi < 2; mi++)
#pragma unroll
      for (int e = 0; e < 4; e++) {
        int row = a0 + w * 32 + mi * 16 + g * 4 + e;
        atomicMin(&minOut[(size_t)b * N_ + row], fkey(rmin[mi][e]));
      }
  }
}

// Kernel 3: per-slice max of (norm + rmin), atomicMax into gmax[dir].
__global__ __launch_bounds__(256) void final1_kernel(
    const unsigned* __restrict__ minN, const unsigned* __restrict__ minM,
    const float* __restrict__ x2, const float* __restrict__ y2,
    unsigned* __restrict__ gmax) {
  int dir = blockIdx.x >> 6;
  int blk = blockIdx.x & 63;
  const unsigned* src = dir ? minM : minN;
  const float* nrm = dir ? y2 : x2;
  size_t base = (size_t)blk * 512;
  float mx = -INFINITY;
  for (int i = threadIdx.x; i < 512; i += 256)
    mx = fmaxf(mx, nrm[base + i] + funkey(src[base + i]));
#pragma unroll
  for (int mask = 1; mask < 64; mask <<= 1) mx = fmaxf(mx, __shfl_xor(mx, mask));
  __shared__ float sm[4];
  if ((threadIdx.x & 63) == 0) sm[threadIdx.x >> 6] = mx;
  __syncthreads();
  if (threadIdx.x == 0) {
    mx = fmaxf(fmaxf(sm[0], sm[1]), fmaxf(sm[2], sm[3]));
    atomicMax(&gmax[dir], fkey(mx));
  }
}

__global__ void final2_kernel(const unsigned* __restrict__ gmax, float* __restrict__ out) {
  if (threadIdx.x == 0)
    out[0] = sqrtf(fmaxf(funkey(gmax[0]), 1e-12f)) +
             sqrtf(fmaxf(funkey(gmax[1]), 1e-12f));
}

extern "C" void kernel_launch(void* const* d_in, const int* in_sizes, int n_in,
                              void* d_out, int out_size, void* d_ws, size_t ws_size,
                              hipStream_t stream) {
  const float* pred = (const float*)d_in[0];
  const float* label = (const float*)d_in[1];
  char* ws = (char*)d_ws;

  const size_t bfBytes = (size_t)BNT * D_ * 2;  // 4 MB per array
  const size_t needFast = 2 * bfBytes + (size_t)(BNT + BMT) * 8 + 64;

  if (ws_size >= needFast) {
    unsigned short* predbf = (unsigned short*)ws;
    unsigned short* labelbf = (unsigned short*)(ws + bfBytes);
    float* x2 = (float*)(ws + 2 * bfBytes);
    float* y2 = x2 + BNT;
    unsigned* minN = (unsigned*)(y2 + BMT);
    unsigned* minM = minN + BNT;
    unsigned* gmax = minM + BMT;

    prep_kernel<true><<<(BNT + BMT) / 16, 256, 0, stream>>>(
        pred, label, predbf, labelbf, x2, y2, minN, minM, gmax);
    pass_kernel<true><<<dim3(N_ / TILE, NCHUNK, B_), 256, 0, stream>>>(
        predbf, labelbf, y2, minN);
    pass_kernel<true><<<dim3(M_ / TILE, NCHUNK, B_), 256, 0, stream>>>(
        labelbf, predbf, x2, minM);
    final1_kernel<<<128, 256, 0, stream>>>(minN, minM, x2, y2, gmax);
    final2_kernel<<<1, 64, 0, stream>>>(gmax, (float*)d_out);
  } else {
    // fallback: no pre-converted bf16 arrays; stage+convert in-kernel
    float* x2 = (float*)ws;
    float* y2 = x2 + BNT;
    unsigned* minN = (unsigned*)(y2 + BMT);
    unsigned* minM = minN + BNT;
    unsigned* gmax = minM + BMT;

    prep_kernel<false><<<(BNT + BMT) / 16, 256, 0, stream>>>(
        pred, label, nullptr, nullptr, x2, y2, minN, minM, gmax);
    pass_kernel<false><<<dim3(N_ / TILE, NCHUNK, B_), 256, 0, stream>>>(
        pred, label, y2, minN);
    pass_kernel<false><<<dim3(M_ / TILE, NCHUNK, B_), 256, 0, stream>>>(
        label, pred, x2, minM);
    final1_kernel<<<128, 256, 0, stream>>>(minN, minM, x2, y2, gmax);
    final2_kernel<<<1, 64, 0, stream>>>(gmax, (float*)d_out);
  }
}